// Round 5
// baseline (9666.043 us; speedup 1.0000x reference)
//
#include <hip/hip_runtime.h>
#include <math.h>

#define BB 32
#define SS 65536
#define CC 20
#define NM 16
#define HH 128
#define RP 264   // DFT LDS row pitch (bf16 elems)
#define WP 72    // transposed-tile row pitch (bf16 elems): 36 dwords; b128-aligned rows

using short8  = __attribute__((ext_vector_type(8))) short;
using floatx4 = __attribute__((ext_vector_type(4))) float;

__device__ __forceinline__ unsigned short f2bf(float f) {
    union { float f; unsigned u; } v; v.f = f;
    unsigned u = v.u;
    return (unsigned short)((u + 0x7FFFu + ((u >> 16) & 1u)) >> 16);   // RNE
}
__device__ __forceinline__ float bf2f(unsigned short h) {
    union { unsigned u; float f; } v; v.u = ((unsigned)h) << 16; return v.f;
}

// Branchless gelu: erf via Abramowitz-Stegun 7.1.26 (abs err <= 1.5e-7)
__device__ __forceinline__ float gelu_fast(float v) {
    float z = fabsf(v) * 0.7071067811865476f;
    float t = __builtin_amdgcn_rcpf(1.0f + 0.3275911f * z);
    float poly = t * (0.254829592f + t * (-0.284496736f +
                 t * (1.421413741f + t * (-1.453152027f + t * 1.061405429f))));
    float e = __expf(-z * z);
    float erfz = 1.0f - poly * e;          // erf(|v|/sqrt2), >=0
    float se = copysignf(erfz, v);
    return 0.5f * v * (1.0f + se);
}

// ---------------- k_prep: 1/max(point_data) + zero cP accumulators ----------
__global__ __launch_bounds__(256) void k_prep(const float* __restrict__ pd,
                                              float* __restrict__ invmax,
                                              float* __restrict__ cP) {
    if (blockIdx.x == 0) {
        __shared__ float red[256];
        int t = threadIdx.x;
        float m = -1e30f;
        for (int i = t; i < SS; i += 256) m = fmaxf(m, pd[i]);
        red[t] = m; __syncthreads();
        for (int off = 128; off > 0; off >>= 1) {
            if (t < off) red[t] = fmaxf(red[t], red[t + off]);
            __syncthreads();
        }
        if (t == 0) invmax[0] = 1.0f / red[0];
    } else {
        int idx = (blockIdx.x - 1) * 256 + threadIdx.x;   // 320*256 = 4*32*640
        cP[idx] = 0.0f;
    }
}

// ---------------- shared DFT tail: LDS-staged MFMA partial DFT --------------
__device__ __forceinline__ void dft_phase(unsigned short* sh_hA, unsigned short* sh_ph,
                                          int tid, float* cPdst) {
    int wave = tid >> 6, lane = tid & 63;
    int quad = lane >> 4, frow = lane & 15;
    floatx4 acc00 = {0.f,0.f,0.f,0.f}, acc01 = {0.f,0.f,0.f,0.f};
    floatx4 acc10 = {0.f,0.f,0.f,0.f}, acc11 = {0.f,0.f,0.f,0.f};
    int kb = wave * 64 + quad * 8;
    #pragma unroll
    for (int kc = 0; kc < 2; ++kc) {
        int k = kb + kc * 32;
        short8 a0 = *(const short8*)(sh_hA + frow * RP + k);
        short8 a1 = *(const short8*)(sh_hA + (16 + frow) * RP + k);
        short8 bc = *(const short8*)(sh_ph + frow * RP + k);
        short8 bs = *(const short8*)(sh_ph + (16 + frow) * RP + k);
        acc00 = __builtin_amdgcn_mfma_f32_16x16x32_bf16(a0, bc, acc00, 0, 0, 0);
        acc01 = __builtin_amdgcn_mfma_f32_16x16x32_bf16(a0, bs, acc01, 0, 0, 0);
        acc10 = __builtin_amdgcn_mfma_f32_16x16x32_bf16(a1, bc, acc10, 0, 0, 0);
        acc11 = __builtin_amdgcn_mfma_f32_16x16x32_bf16(a1, bs, acc11, 0, 0, 0);
    }
    __syncthreads();
    float* red = (float*)sh_hA;
    #pragma unroll
    for (int r = 0; r < 4; ++r) {
        red[wave * 1024 + 0 * 256 + r * 64 + lane] = acc00[r];
        red[wave * 1024 + 1 * 256 + r * 64 + lane] = acc01[r];
        red[wave * 1024 + 2 * 256 + r * 64 + lane] = acc10[r];
        red[wave * 1024 + 3 * 256 + r * 64 + lane] = acc11[r];
    }
    __syncthreads();
    #pragma unroll
    for (int ii = 0; ii < 4; ++ii) {
        int idx = ii * 256 + tid;
        float v = red[idx] + red[1024 + idx] + red[2048 + idx] + red[3072 + idx];
        int f = idx >> 8;
        int r = (idx >> 6) & 3, ln = idx & 63;
        int o = (f >> 1) * 16 + (ln >> 4) * 4 + r;   // D row = quad*4+reg
        int m = ln & 15;                              // D col = lane&15
        if (o < CC) atomicAdd(cPdst + (f & 1) * 320 + o * 16 + m, v);
    }
}

// ---------------- k_fc0_dft ----------------
__global__ __launch_bounds__(256, 4) void k_fc0_dft(const float* __restrict__ x,
        const float* __restrict__ pd, const float* __restrict__ w,
        const float* __restrict__ bias, const float* __restrict__ invmax,
        float* __restrict__ h, float* __restrict__ cP0) {
    __shared__ __align__(16) unsigned short sh_hA[32 * RP];
    __shared__ __align__(16) unsigned short sh_ph[32 * RP];
    __shared__ float lw[2 * CC], lb[CC];
    int tid = threadIdx.x;
    if (tid < 2 * CC) lw[tid] = w[tid];
    if (tid < CC) lb[tid] = bias[tid];
    {
        unsigned* z = (unsigned*)(sh_hA + CC * RP);
        for (int i = tid; i < (32 - CC) * RP / 2; i += 256) z[i] = 0;
    }
    __syncthreads();
    int b = blockIdx.y;
    int s = blockIdx.x * 256 + tid;
    float xv = x[(size_t)b * SS + s];
    float g  = pd[s] * invmax[0];
    float* hp = h + (size_t)b * CC * SS + s;
    float u = (float)s * (1.0f / 32768.0f);
    float s1, c1; sincospif(u, &s1, &c1);
    float cm = 1.0f, sm = 0.0f;
    #pragma unroll
    for (int m = 0; m < NM; ++m) {
        sh_ph[m * RP + tid]        = f2bf(cm);
        sh_ph[(16 + m) * RP + tid] = f2bf(sm);
        float cn = cm * c1 - sm * s1;
        sm = sm * c1 + cm * s1;
        cm = cn;
    }
    #pragma unroll
    for (int c = 0; c < CC; ++c) {
        float v = xv * lw[c] + g * lw[CC + c] + lb[c];
        hp[(size_t)c * SS] = v;
        sh_hA[c * RP + tid] = f2bf(v);
    }
    __syncthreads();
    dft_phase(sh_hA, sh_ph, tid, cP0 + (size_t)b * 640);
}

// ---------------- k_point_dft (layers 0..2: gelu + next-layer DFT) ----------
__global__ __launch_bounds__(256, 3) void k_point_dft(float* __restrict__ h,
        const float* __restrict__ ww, const float* __restrict__ wb,
        const float* __restrict__ cA, const float* __restrict__ cB,
        float* __restrict__ cPn) {
    __shared__ __align__(16) unsigned short sh_hA[32 * RP];
    __shared__ __align__(16) unsigned short sh_ph[32 * RP];
    __shared__ float lww[CC * CC], lwb[CC], lA[CC * NM], lB[CC * NM];
    int tid = threadIdx.x;
    int b = blockIdx.y;
    for (int i = tid; i < CC * CC; i += 256) lww[i] = ww[i];
    if (tid < CC) lwb[tid] = wb[tid];
    for (int i = tid; i < CC * NM; i += 256) { lA[i] = cA[b * CC * NM + i]; lB[i] = cB[b * CC * NM + i]; }
    {
        unsigned* z = (unsigned*)(sh_hA + CC * RP);
        for (int i = tid; i < (32 - CC) * RP / 2; i += 256) z[i] = 0;
    }
    __syncthreads();
    int s = blockIdx.x * 256 + tid;
    float* hp = h + (size_t)b * CC * SS + s;
    float u = (float)s * (1.0f / 32768.0f);
    float s1, c1; sincospif(u, &s1, &c1);
    float cm[NM], sm[NM];
    cm[0] = 1.0f; sm[0] = 0.0f;
    #pragma unroll
    for (int m = 1; m < NM; ++m) {
        cm[m] = cm[m - 1] * c1 - sm[m - 1] * s1;
        sm[m] = sm[m - 1] * c1 + cm[m - 1] * s1;
    }
    #pragma unroll
    for (int m = 0; m < NM; ++m) {
        sh_ph[m * RP + tid]        = f2bf(cm[m]);
        sh_ph[(16 + m) * RP + tid] = f2bf(sm[m]);
    }
    float hv[CC];
    #pragma unroll
    for (int c = 0; c < CC; ++c) hv[c] = hp[(size_t)c * SS];
    #pragma unroll 2
    for (int o = 0; o < CC; ++o) {
        float a = lwb[o];
        #pragma unroll
        for (int c = 0; c < CC; ++c) a += lww[o * CC + c] * hv[c];
        #pragma unroll
        for (int m = 0; m < NM; ++m)
            a += lA[o * NM + m] * cm[m] + lB[o * NM + m] * sm[m];
        a = gelu_fast(a);
        hp[(size_t)o * SS] = a;
        sh_hA[o * RP + tid] = f2bf(a);
    }
    __syncthreads();
    dft_phase(sh_hA, sh_ph, tid, cPn + (size_t)b * 640);
}

// ---------------- k_mix ----------------
__global__ __launch_bounds__(320) void k_mix(const float* __restrict__ cP,
                                             const float* __restrict__ wre, const float* __restrict__ wim,
                                             float* __restrict__ cA, float* __restrict__ cB) {
    int b = blockIdx.x, tid = threadIdx.x;
    __shared__ float PQ[640];
    const float* base = cP + (size_t)b * 640;
    int i = tid >> 4, m = tid & 15;
    PQ[i * 32 + m]      = base[tid];
    PQ[i * 32 + 16 + m] = base[320 + tid];
    __syncthreads();
    int o = i;
    float reY = 0.f, imY = 0.f;
    #pragma unroll
    for (int c = 0; c < CC; ++c) {
        float P = PQ[c * 32 + m], Q = PQ[c * 32 + 16 + m];
        float wr = wre[(size_t)(c * CC + o) * NM + m];
        float wi = wim[(size_t)(c * CC + o) * NM + m];
        reY += P * wr + Q * wi;
        imY += P * wi - Q * wr;
    }
    const float invS = 1.0f / (float)SS;
    float a, bb;
    if (m == 0) { a = reY * invS; bb = 0.0f; }
    else        { a = 2.0f * reY * invS; bb = -2.0f * imY * invS; }
    cA[(size_t)(b * CC + o) * NM + m] = a;
    cB[(size_t)(b * CC + o) * NM + m] = bb;
}

// ---------------- k_point_final: layer-3 point op fused with fc1/gelu/fc2 ---
// Block: 256 thr, 256 s rows. Thread tid computes all 20 channels of its s,
// hi/lo splits them, writes ONE hT row as 8x ds_write_b128 (conflict-free:
// dword = 4*tid + 4*ch + k -> 8 lanes per bank-group). h is never written.
__global__ __launch_bounds__(256, 2) void k_point_final(const float* __restrict__ h,
        const float* __restrict__ ww, const float* __restrict__ wb,
        const float* __restrict__ cA, const float* __restrict__ cB,
        const float* __restrict__ w1, const float* __restrict__ b1,
        const float* __restrict__ w2, const float* __restrict__ b2,
        float* __restrict__ out) {
    __shared__ __align__(16) unsigned short hT[256 * WP];   // 36.9 KB
    __shared__ __align__(16) unsigned short w1T[128 * WP];  // 18.4 KB
    __shared__ float lww[CC * CC], lwb[CC], lA[CC * NM], lB[CC * NM];
    __shared__ float lb1[HH], lw2[HH], outS[256];
    int tid = threadIdx.x;
    int b = blockIdx.y;
    // phase 1: small arrays + zero w1T
    for (int i = tid; i < CC * CC; i += 256) lww[i] = ww[i];
    if (tid < CC) lwb[tid] = wb[tid];
    for (int i = tid; i < CC * NM; i += 256) { lA[i] = cA[b * CC * NM + i]; lB[i] = cB[b * CC * NM + i]; }
    if (tid < HH) { lb1[tid] = b1[tid]; lw2[tid] = w2[tid]; }
    {
        unsigned* z = (unsigned*)w1T;
        for (int i = tid; i < 128 * WP / 2; i += 256) z[i] = 0;
    }
    __syncthreads();
    // phase 2a: stage w1 transposed hi/lo
    for (int idx = tid; idx < CC * HH; idx += 256) {
        int c = idx / HH, j = idx - c * HH;       // w1[c][j]
        float v = w1[idx];
        unsigned short hi = f2bf(v);
        w1T[j * WP + c]      = hi;
        w1T[j * WP + 32 + c] = f2bf(v - bf2f(hi));
    }
    // phase 2b: layer-3 point op (no gelu), pack own hT row
    int s = blockIdx.x * 256 + tid;
    const float* hp = h + (size_t)b * CC * SS + s;
    float u = (float)s * (1.0f / 32768.0f);
    float s1, c1; sincospif(u, &s1, &c1);
    float cm[NM], sm[NM];
    cm[0] = 1.0f; sm[0] = 0.0f;
    #pragma unroll
    for (int m = 1; m < NM; ++m) {
        cm[m] = cm[m - 1] * c1 - sm[m - 1] * s1;
        sm[m] = sm[m - 1] * c1 + cm[m - 1] * s1;
    }
    float hv[CC];
    #pragma unroll
    for (int c = 0; c < CC; ++c) hv[c] = hp[(size_t)c * SS];
    short8 rowf[8];
    #pragma unroll
    for (int ch = 0; ch < 8; ++ch) rowf[ch] = (short8){0,0,0,0,0,0,0,0};
    #pragma unroll 2
    for (int o = 0; o < CC; ++o) {
        float a = lwb[o];
        #pragma unroll
        for (int c = 0; c < CC; ++c) a += lww[o * CC + c] * hv[c];
        #pragma unroll
        for (int m = 0; m < NM; ++m)
            a += lA[o * NM + m] * cm[m] + lB[o * NM + m] * sm[m];
        unsigned short hi = f2bf(a);
        rowf[o >> 3][o & 7]            = (short)hi;
        rowf[4 + (o >> 3)][o & 7]      = (short)f2bf(a - bf2f(hi));
    }
    #pragma unroll
    for (int ch = 0; ch < 8; ++ch)
        *(short8*)(hT + tid * WP + ch * 8) = rowf[ch];
    __syncthreads();
    // phase 3: MFMA fc1 (hi/lo) + gelu + fc2
    int wave = tid >> 6, lane = tid & 63;
    int col = lane & 15, quad = lane >> 4;
    short8 bhi[8], blo[8];
    #pragma unroll
    for (int nt = 0; nt < 8; ++nt) {
        bhi[nt] = *(const short8*)(w1T + (nt * 16 + col) * WP + quad * 8);
        blo[nt] = *(const short8*)(w1T + (nt * 16 + col) * WP + 32 + quad * 8);
    }
    float lb1r[8], w2r[8];
    #pragma unroll
    for (int nt = 0; nt < 8; ++nt) { lb1r[nt] = lb1[nt * 16 + col]; w2r[nt] = lw2[nt * 16 + col]; }
    float b2v = b2[0];
    #pragma unroll
    for (int mt = 0; mt < 4; ++mt) {
        int srow = wave * 64 + mt * 16 + col;     // A row m = lane&15
        short8 ahi = *(const short8*)(hT + srow * WP + quad * 8);
        short8 alo = *(const short8*)(hT + srow * WP + 32 + quad * 8);
        float part[4] = {0.f, 0.f, 0.f, 0.f};
        #pragma unroll
        for (int nt = 0; nt < 8; ++nt) {
            floatx4 a = {0.f, 0.f, 0.f, 0.f};
            a = __builtin_amdgcn_mfma_f32_16x16x32_bf16(ahi, bhi[nt], a, 0, 0, 0);
            a = __builtin_amdgcn_mfma_f32_16x16x32_bf16(ahi, blo[nt], a, 0, 0, 0);
            a = __builtin_amdgcn_mfma_f32_16x16x32_bf16(alo, bhi[nt], a, 0, 0, 0);
            #pragma unroll
            for (int r = 0; r < 4; ++r) {
                float t = gelu_fast(a[r] + lb1r[nt]);
                part[r] += t * w2r[nt];
            }
        }
        #pragma unroll
        for (int r = 0; r < 4; ++r) {
            float p = part[r];
            p += __shfl_xor(p, 1, 64);
            p += __shfl_xor(p, 2, 64);
            p += __shfl_xor(p, 4, 64);
            p += __shfl_xor(p, 8, 64);
            if (col == 0) outS[wave * 64 + mt * 16 + quad * 4 + r] = p + b2v;
        }
    }
    __syncthreads();
    out[(size_t)b * SS + blockIdx.x * 256 + tid] = outS[tid];
}

extern "C" void kernel_launch(void* const* d_in, const int* in_sizes, int n_in,
                              void* d_out, int out_size, void* d_ws, size_t ws_size,
                              hipStream_t stream) {
    (void)in_sizes; (void)n_in; (void)out_size; (void)ws_size;
    const float* x    = (const float*)d_in[0];
    const float* pd   = (const float*)d_in[1];
    const float* fc0w = (const float*)d_in[2];
    const float* fc0b = (const float*)d_in[3];
    const float* fc1w = (const float*)d_in[4];
    const float* fc1b = (const float*)d_in[5];
    const float* fc2w = (const float*)d_in[6];
    const float* fc2b = (const float*)d_in[7];

    char* ws = (char*)d_ws;
    float* h = (float*)ws;
    size_t off = (size_t)BB * CC * SS * 4;
    float* cP = (float*)(ws + off); off += (size_t)4 * BB * 640 * 4;
    float* cA = (float*)(ws + off); off += (size_t)BB * CC * NM * 4;
    float* cB = (float*)(ws + off); off += (size_t)BB * CC * NM * 4;
    float* invmax = (float*)(ws + off); off += 256;

    dim3 gBS(SS / 256, BB);

    k_prep<<<321, 256, 0, stream>>>(pd, invmax, cP);
    k_fc0_dft<<<gBS, 256, 0, stream>>>(x, pd, fc0w, fc0b, invmax, h, cP);

    for (int l = 0; l < 3; ++l) {
        const float* wre = (const float*)d_in[8 + 4 * l];
        const float* wim = (const float*)d_in[9 + 4 * l];
        const float* ww  = (const float*)d_in[10 + 4 * l];
        const float* wb  = (const float*)d_in[11 + 4 * l];
        k_mix<<<BB, 320, 0, stream>>>(cP + (size_t)l * BB * 640, wre, wim, cA, cB);
        k_point_dft<<<gBS, 256, 0, stream>>>(h, ww, wb, cA, cB,
                                             cP + (size_t)(l + 1) * BB * 640);
    }
    {   // layer 3 fused with fc1/gelu/fc2
        const float* wre = (const float*)d_in[20];
        const float* wim = (const float*)d_in[21];
        const float* ww  = (const float*)d_in[22];
        const float* wb  = (const float*)d_in[23];
        k_mix<<<BB, 320, 0, stream>>>(cP + (size_t)3 * BB * 640, wre, wim, cA, cB);
        k_point_final<<<gBS, 256, 0, stream>>>(h, ww, wb, cA, cB,
                                               fc1w, fc1b, fc2w, fc2b, (float*)d_out);
    }
}

// Round 6
// 965.019 us; speedup vs baseline: 10.0164x; 10.0164x over previous
//
#include <hip/hip_runtime.h>
#include <math.h>

#define BB 32
#define SS 65536
#define CC 20
#define NM 16
#define HH 128
#define RP 264   // DFT LDS row pitch (bf16 elems)
#define WP 72    // transposed-tile row pitch (bf16 elems): 36 dwords; b128-aligned rows

using short8  = __attribute__((ext_vector_type(8))) short;
using floatx4 = __attribute__((ext_vector_type(4))) float;

__device__ __forceinline__ unsigned short f2bf(float f) {
    union { float f; unsigned u; } v; v.f = f;
    unsigned u = v.u;
    return (unsigned short)((u + 0x7FFFu + ((u >> 16) & 1u)) >> 16);   // RNE
}
__device__ __forceinline__ float bf2f(unsigned short h) {
    union { unsigned u; float f; } v; v.u = ((unsigned)h) << 16; return v.f;
}

// Branchless gelu: erf via Abramowitz-Stegun 7.1.26 (abs err <= 1.5e-7)
__device__ __forceinline__ float gelu_fast(float v) {
    float z = fabsf(v) * 0.7071067811865476f;
    float t = __builtin_amdgcn_rcpf(1.0f + 0.3275911f * z);
    float poly = t * (0.254829592f + t * (-0.284496736f +
                 t * (1.421413741f + t * (-1.453152027f + t * 1.061405429f))));
    float e = __expf(-z * z);
    float erfz = 1.0f - poly * e;          // erf(|v|/sqrt2), >=0
    float se = copysignf(erfz, v);
    return 0.5f * v * (1.0f + se);
}

// ---------------- k_prep: 1/max(point_data) + zero cP accumulators ----------
__global__ __launch_bounds__(256) void k_prep(const float* __restrict__ pd,
                                              float* __restrict__ invmax,
                                              float* __restrict__ cP) {
    if (blockIdx.x == 0) {
        __shared__ float red[256];
        int t = threadIdx.x;
        float m = -1e30f;
        for (int i = t; i < SS; i += 256) m = fmaxf(m, pd[i]);
        red[t] = m; __syncthreads();
        for (int off = 128; off > 0; off >>= 1) {
            if (t < off) red[t] = fmaxf(red[t], red[t + off]);
            __syncthreads();
        }
        if (t == 0) invmax[0] = 1.0f / red[0];
    } else {
        int idx = (blockIdx.x - 1) * 256 + threadIdx.x;   // 320*256 = 4*32*640
        cP[idx] = 0.0f;
    }
}

// ---------------- shared DFT tail: LDS-staged MFMA partial DFT --------------
__device__ __forceinline__ void dft_phase(unsigned short* sh_hA, unsigned short* sh_ph,
                                          int tid, float* cPdst) {
    int wave = tid >> 6, lane = tid & 63;
    int quad = lane >> 4, frow = lane & 15;
    floatx4 acc00 = {0.f,0.f,0.f,0.f}, acc01 = {0.f,0.f,0.f,0.f};
    floatx4 acc10 = {0.f,0.f,0.f,0.f}, acc11 = {0.f,0.f,0.f,0.f};
    int kb = wave * 64 + quad * 8;
    #pragma unroll
    for (int kc = 0; kc < 2; ++kc) {
        int k = kb + kc * 32;
        short8 a0 = *(const short8*)(sh_hA + frow * RP + k);
        short8 a1 = *(const short8*)(sh_hA + (16 + frow) * RP + k);
        short8 bc = *(const short8*)(sh_ph + frow * RP + k);
        short8 bs = *(const short8*)(sh_ph + (16 + frow) * RP + k);
        acc00 = __builtin_amdgcn_mfma_f32_16x16x32_bf16(a0, bc, acc00, 0, 0, 0);
        acc01 = __builtin_amdgcn_mfma_f32_16x16x32_bf16(a0, bs, acc01, 0, 0, 0);
        acc10 = __builtin_amdgcn_mfma_f32_16x16x32_bf16(a1, bc, acc10, 0, 0, 0);
        acc11 = __builtin_amdgcn_mfma_f32_16x16x32_bf16(a1, bs, acc11, 0, 0, 0);
    }
    __syncthreads();
    float* red = (float*)sh_hA;
    #pragma unroll
    for (int r = 0; r < 4; ++r) {
        red[wave * 1024 + 0 * 256 + r * 64 + lane] = acc00[r];
        red[wave * 1024 + 1 * 256 + r * 64 + lane] = acc01[r];
        red[wave * 1024 + 2 * 256 + r * 64 + lane] = acc10[r];
        red[wave * 1024 + 3 * 256 + r * 64 + lane] = acc11[r];
    }
    __syncthreads();
    #pragma unroll
    for (int ii = 0; ii < 4; ++ii) {
        int idx = ii * 256 + tid;
        float v = red[idx] + red[1024 + idx] + red[2048 + idx] + red[3072 + idx];
        int f = idx >> 8;
        int r = (idx >> 6) & 3, ln = idx & 63;
        int o = (f >> 1) * 16 + (ln >> 4) * 4 + r;   // D row = quad*4+reg
        int m = ln & 15;                              // D col = lane&15
        if (o < CC) atomicAdd(cPdst + (f & 1) * 320 + o * 16 + m, v);
    }
}

// ---------------- k_fc0_dft ----------------
__global__ __launch_bounds__(256, 4) void k_fc0_dft(const float* __restrict__ x,
        const float* __restrict__ pd, const float* __restrict__ w,
        const float* __restrict__ bias, const float* __restrict__ invmax,
        float* __restrict__ h, float* __restrict__ cP0) {
    __shared__ __align__(16) unsigned short sh_hA[32 * RP];
    __shared__ __align__(16) unsigned short sh_ph[32 * RP];
    __shared__ float lw[2 * CC], lb[CC];
    int tid = threadIdx.x;
    if (tid < 2 * CC) lw[tid] = w[tid];
    if (tid < CC) lb[tid] = bias[tid];
    {
        unsigned* z = (unsigned*)(sh_hA + CC * RP);
        for (int i = tid; i < (32 - CC) * RP / 2; i += 256) z[i] = 0;
    }
    __syncthreads();
    int b = blockIdx.y;
    int s = blockIdx.x * 256 + tid;
    float xv = x[(size_t)b * SS + s];
    float g  = pd[s] * invmax[0];
    float* hp = h + (size_t)b * CC * SS + s;
    float u = (float)s * (1.0f / 32768.0f);
    float s1, c1; sincospif(u, &s1, &c1);
    float cm = 1.0f, sm = 0.0f;
    #pragma unroll
    for (int m = 0; m < NM; ++m) {
        sh_ph[m * RP + tid]        = f2bf(cm);
        sh_ph[(16 + m) * RP + tid] = f2bf(sm);
        float cn = cm * c1 - sm * s1;
        sm = sm * c1 + cm * s1;
        cm = cn;
    }
    #pragma unroll
    for (int c = 0; c < CC; ++c) {
        float v = xv * lw[c] + g * lw[CC + c] + lb[c];
        hp[(size_t)c * SS] = v;
        sh_hA[c * RP + tid] = f2bf(v);
    }
    __syncthreads();
    dft_phase(sh_hA, sh_ph, tid, cP0 + (size_t)b * 640);
}

// ---------------- k_point_dft (layers 0..2: gelu + next-layer DFT) ----------
__global__ __launch_bounds__(256, 3) void k_point_dft(float* __restrict__ h,
        const float* __restrict__ ww, const float* __restrict__ wb,
        const float* __restrict__ cA, const float* __restrict__ cB,
        float* __restrict__ cPn) {
    __shared__ __align__(16) unsigned short sh_hA[32 * RP];
    __shared__ __align__(16) unsigned short sh_ph[32 * RP];
    __shared__ float lww[CC * CC], lwb[CC], lA[CC * NM], lB[CC * NM];
    int tid = threadIdx.x;
    int b = blockIdx.y;
    for (int i = tid; i < CC * CC; i += 256) lww[i] = ww[i];
    if (tid < CC) lwb[tid] = wb[tid];
    for (int i = tid; i < CC * NM; i += 256) { lA[i] = cA[b * CC * NM + i]; lB[i] = cB[b * CC * NM + i]; }
    {
        unsigned* z = (unsigned*)(sh_hA + CC * RP);
        for (int i = tid; i < (32 - CC) * RP / 2; i += 256) z[i] = 0;
    }
    __syncthreads();
    int s = blockIdx.x * 256 + tid;
    float* hp = h + (size_t)b * CC * SS + s;
    float u = (float)s * (1.0f / 32768.0f);
    float s1, c1; sincospif(u, &s1, &c1);
    float cm[NM], sm[NM];
    cm[0] = 1.0f; sm[0] = 0.0f;
    #pragma unroll
    for (int m = 1; m < NM; ++m) {
        cm[m] = cm[m - 1] * c1 - sm[m - 1] * s1;
        sm[m] = sm[m - 1] * c1 + cm[m - 1] * s1;
    }
    #pragma unroll
    for (int m = 0; m < NM; ++m) {
        sh_ph[m * RP + tid]        = f2bf(cm[m]);
        sh_ph[(16 + m) * RP + tid] = f2bf(sm[m]);
    }
    float hv[CC];
    #pragma unroll
    for (int c = 0; c < CC; ++c) hv[c] = hp[(size_t)c * SS];
    #pragma unroll 2
    for (int o = 0; o < CC; ++o) {
        float a = lwb[o];
        #pragma unroll
        for (int c = 0; c < CC; ++c) a += lww[o * CC + c] * hv[c];
        #pragma unroll
        for (int m = 0; m < NM; ++m)
            a += lA[o * NM + m] * cm[m] + lB[o * NM + m] * sm[m];
        a = gelu_fast(a);
        hp[(size_t)o * SS] = a;
        sh_hA[o * RP + tid] = f2bf(a);
    }
    __syncthreads();
    dft_phase(sh_hA, sh_ph, tid, cPn + (size_t)b * 640);
}

// ---------------- k_mix ----------------
__global__ __launch_bounds__(320) void k_mix(const float* __restrict__ cP,
                                             const float* __restrict__ wre, const float* __restrict__ wim,
                                             float* __restrict__ cA, float* __restrict__ cB) {
    int b = blockIdx.x, tid = threadIdx.x;
    __shared__ float PQ[640];
    const float* base = cP + (size_t)b * 640;
    int i = tid >> 4, m = tid & 15;
    PQ[i * 32 + m]      = base[tid];
    PQ[i * 32 + 16 + m] = base[320 + tid];
    __syncthreads();
    int o = i;
    float reY = 0.f, imY = 0.f;
    #pragma unroll
    for (int c = 0; c < CC; ++c) {
        float P = PQ[c * 32 + m], Q = PQ[c * 32 + 16 + m];
        float wr = wre[(size_t)(c * CC + o) * NM + m];
        float wi = wim[(size_t)(c * CC + o) * NM + m];
        reY += P * wr + Q * wi;
        imY += P * wi - Q * wr;
    }
    const float invS = 1.0f / (float)SS;
    float a, bb;
    if (m == 0) { a = reY * invS; bb = 0.0f; }
    else        { a = 2.0f * reY * invS; bb = -2.0f * imY * invS; }
    cA[(size_t)(b * CC + o) * NM + m] = a;
    cB[(size_t)(b * CC + o) * NM + m] = bb;
}

// ---------------- k_point_final: layer-3 point op fused with fc1/gelu/fc2 ---
// Block: 256 thr, 256 s rows. Thread tid computes all 20 channels of its s,
// hi/lo splits them, writes ONE hT row as 8x ds_write_b128.
// NOTE: the o-loop MUST be fully unrolled — rowf is indexed by o; partial
// unroll makes the index dynamic and demotes rowf to scratch (R5: 1.5 GB
// scratch writes, 9.1 ms dispatch).
__global__ __launch_bounds__(256, 2) void k_point_final(const float* __restrict__ h,
        const float* __restrict__ ww, const float* __restrict__ wb,
        const float* __restrict__ cA, const float* __restrict__ cB,
        const float* __restrict__ w1, const float* __restrict__ b1,
        const float* __restrict__ w2, const float* __restrict__ b2,
        float* __restrict__ out) {
    __shared__ __align__(16) unsigned short hT[256 * WP];   // 36.9 KB
    __shared__ __align__(16) unsigned short w1T[128 * WP];  // 18.4 KB
    __shared__ float lww[CC * CC], lwb[CC], lA[CC * NM], lB[CC * NM];
    __shared__ float lb1[HH], lw2[HH], outS[256];
    int tid = threadIdx.x;
    int b = blockIdx.y;
    // phase 1: small arrays + zero w1T
    for (int i = tid; i < CC * CC; i += 256) lww[i] = ww[i];
    if (tid < CC) lwb[tid] = wb[tid];
    for (int i = tid; i < CC * NM; i += 256) { lA[i] = cA[b * CC * NM + i]; lB[i] = cB[b * CC * NM + i]; }
    if (tid < HH) { lb1[tid] = b1[tid]; lw2[tid] = w2[tid]; }
    {
        unsigned* z = (unsigned*)w1T;
        for (int i = tid; i < 128 * WP / 2; i += 256) z[i] = 0;
    }
    __syncthreads();
    // phase 2a: stage w1 transposed hi/lo
    for (int idx = tid; idx < CC * HH; idx += 256) {
        int c = idx / HH, j = idx - c * HH;       // w1[c][j]
        float v = w1[idx];
        unsigned short hi = f2bf(v);
        w1T[j * WP + c]      = hi;
        w1T[j * WP + 32 + c] = f2bf(v - bf2f(hi));
    }
    // phase 2b: layer-3 point op (no gelu), pack own hT row
    int s = blockIdx.x * 256 + tid;
    const float* hp = h + (size_t)b * CC * SS + s;
    float u = (float)s * (1.0f / 32768.0f);
    float s1, c1; sincospif(u, &s1, &c1);
    float cm[NM], sm[NM];
    cm[0] = 1.0f; sm[0] = 0.0f;
    #pragma unroll
    for (int m = 1; m < NM; ++m) {
        cm[m] = cm[m - 1] * c1 - sm[m - 1] * s1;
        sm[m] = sm[m - 1] * c1 + cm[m - 1] * s1;
    }
    float hv[CC];
    #pragma unroll
    for (int c = 0; c < CC; ++c) hv[c] = hp[(size_t)c * SS];
    short8 rowf[8];
    #pragma unroll
    for (int ch = 0; ch < 8; ++ch) rowf[ch] = (short8){0,0,0,0,0,0,0,0};
    #pragma unroll        // FULL unroll: constant indices into rowf (see note)
    for (int o = 0; o < CC; ++o) {
        float a = lwb[o];
        #pragma unroll
        for (int c = 0; c < CC; ++c) a += lww[o * CC + c] * hv[c];
        #pragma unroll
        for (int m = 0; m < NM; ++m)
            a += lA[o * NM + m] * cm[m] + lB[o * NM + m] * sm[m];
        unsigned short hi = f2bf(a);
        rowf[o >> 3][o & 7]            = (short)hi;
        rowf[4 + (o >> 3)][o & 7]      = (short)f2bf(a - bf2f(hi));
    }
    #pragma unroll
    for (int ch = 0; ch < 8; ++ch)
        *(short8*)(hT + tid * WP + ch * 8) = rowf[ch];
    __syncthreads();
    // phase 3: MFMA fc1 (hi/lo) + gelu + fc2
    int wave = tid >> 6, lane = tid & 63;
    int col = lane & 15, quad = lane >> 4;
    short8 bhi[8], blo[8];
    #pragma unroll
    for (int nt = 0; nt < 8; ++nt) {
        bhi[nt] = *(const short8*)(w1T + (nt * 16 + col) * WP + quad * 8);
        blo[nt] = *(const short8*)(w1T + (nt * 16 + col) * WP + 32 + quad * 8);
    }
    float lb1r[8], w2r[8];
    #pragma unroll
    for (int nt = 0; nt < 8; ++nt) { lb1r[nt] = lb1[nt * 16 + col]; w2r[nt] = lw2[nt * 16 + col]; }
    float b2v = b2[0];
    #pragma unroll
    for (int mt = 0; mt < 4; ++mt) {
        int srow = wave * 64 + mt * 16 + col;     // A row m = lane&15
        short8 ahi = *(const short8*)(hT + srow * WP + quad * 8);
        short8 alo = *(const short8*)(hT + srow * WP + 32 + quad * 8);
        float part[4] = {0.f, 0.f, 0.f, 0.f};
        #pragma unroll
        for (int nt = 0; nt < 8; ++nt) {
            floatx4 a = {0.f, 0.f, 0.f, 0.f};
            a = __builtin_amdgcn_mfma_f32_16x16x32_bf16(ahi, bhi[nt], a, 0, 0, 0);
            a = __builtin_amdgcn_mfma_f32_16x16x32_bf16(ahi, blo[nt], a, 0, 0, 0);
            a = __builtin_amdgcn_mfma_f32_16x16x32_bf16(alo, bhi[nt], a, 0, 0, 0);
            #pragma unroll
            for (int r = 0; r < 4; ++r) {
                float t = gelu_fast(a[r] + lb1r[nt]);
                part[r] += t * w2r[nt];
            }
        }
        #pragma unroll
        for (int r = 0; r < 4; ++r) {
            float p = part[r];
            p += __shfl_xor(p, 1, 64);
            p += __shfl_xor(p, 2, 64);
            p += __shfl_xor(p, 4, 64);
            p += __shfl_xor(p, 8, 64);
            if (col == 0) outS[wave * 64 + mt * 16 + quad * 4 + r] = p + b2v;
        }
    }
    __syncthreads();
    out[(size_t)b * SS + blockIdx.x * 256 + tid] = outS[tid];
}

extern "C" void kernel_launch(void* const* d_in, const int* in_sizes, int n_in,
                              void* d_out, int out_size, void* d_ws, size_t ws_size,
                              hipStream_t stream) {
    (void)in_sizes; (void)n_in; (void)out_size; (void)ws_size;
    const float* x    = (const float*)d_in[0];
    const float* pd   = (const float*)d_in[1];
    const float* fc0w = (const float*)d_in[2];
    const float* fc0b = (const float*)d_in[3];
    const float* fc1w = (const float*)d_in[4];
    const float* fc1b = (const float*)d_in[5];
    const float* fc2w = (const float*)d_in[6];
    const float* fc2b = (const float*)d_in[7];

    char* ws = (char*)d_ws;
    float* h = (float*)ws;
    size_t off = (size_t)BB * CC * SS * 4;
    float* cP = (float*)(ws + off); off += (size_t)4 * BB * 640 * 4;
    float* cA = (float*)(ws + off); off += (size_t)BB * CC * NM * 4;
    float* cB = (float*)(ws + off); off += (size_t)BB * CC * NM * 4;
    float* invmax = (float*)(ws + off); off += 256;

    dim3 gBS(SS / 256, BB);

    k_prep<<<321, 256, 0, stream>>>(pd, invmax, cP);
    k_fc0_dft<<<gBS, 256, 0, stream>>>(x, pd, fc0w, fc0b, invmax, h, cP);

    for (int l = 0; l < 3; ++l) {
        const float* wre = (const float*)d_in[8 + 4 * l];
        const float* wim = (const float*)d_in[9 + 4 * l];
        const float* ww  = (const float*)d_in[10 + 4 * l];
        const float* wb  = (const float*)d_in[11 + 4 * l];
        k_mix<<<BB, 320, 0, stream>>>(cP + (size_t)l * BB * 640, wre, wim, cA, cB);
        k_point_dft<<<gBS, 256, 0, stream>>>(h, ww, wb, cA, cB,
                                             cP + (size_t)(l + 1) * BB * 640);
    }
    {   // layer 3 fused with fc1/gelu/fc2
        const float* wre = (const float*)d_in[20];
        const float* wim = (const float*)d_in[21];
        const float* ww  = (const float*)d_in[22];
        const float* wb  = (const float*)d_in[23];
        k_mix<<<BB, 320, 0, stream>>>(cP + (size_t)3 * BB * 640, wre, wim, cA, cB);
        k_point_final<<<gBS, 256, 0, stream>>>(h, ww, wb, cA, cB,
                                               fc1w, fc1b, fc2w, fc2b, (float*)d_out);
    }
}